// Round 16
// baseline (79.358 us; speedup 1.0000x reference)
//
#include <hip/hip_runtime.h>
#include <hip/hip_bf16.h>
#include <stdint.h>

typedef __attribute__((ext_vector_type(8)))  __bf16   bf16x8;
typedef __attribute__((ext_vector_type(16))) float    f32x16;
typedef __attribute__((ext_vector_type(4)))  float    f32x4;
typedef __attribute__((ext_vector_type(8)))  float    f32x8;

#define NN   2000
#define NK   32
#define NOUT 128
#define NSTEP 130   // packed K: 2048 x-part + 32 dist, /16

#define MFMA32 __builtin_amdgcn_mfma_f32_32x32x16_bf16

// ---------------------------------------------------------------------------
// Prep (verbatim from R6-R11, verified). Blocks [0,NN): x -> xb2 4KB tiles in
// 32x32x16 A-frag order via LDS transpose + dist -> db bf16.
// Blocks [NN,NN+NSTEP): W -> Wf B-frag order.
// xb2 tile byte t*16 holds x[batch=col][f=s*16+half*8+j], t=s*64+half*32+col.
// Wf byte = kstep*4096 + wv*1024 + lane*16; o=wv*32+(lane&31), k=kstep*16+(lane>>5)*8+j.
// ---------------------------------------------------------------------------
__global__ void kprep(const float* __restrict__ x, const float* __restrict__ dist,
                      const float* __restrict__ W,
                      __bf16* __restrict__ xb2, __bf16* __restrict__ db,
                      __bf16* __restrict__ Wf) {
  const int t = threadIdx.x;
  if (blockIdx.x < NN) {
    __shared__ __bf16 sm[32 * 66];
    const int n = blockIdx.x;
    const int bb = t >> 3;
    const int f0 = (t & 7) << 3;
    const float* src = x + ((size_t)bb * NN + n) * 64 + f0;
    f32x8 v = *(const f32x8*)src;
    bf16x8 r;
#pragma unroll
    for (int j = 0; j < 8; ++j) r[j] = (__bf16)v[j];
    *(bf16x8*)&sm[bb * 66 + f0] = r;
    __syncthreads();
    const int col = t & 31, half = (t >> 5) & 1, s = t >> 6;
    bf16x8 o = *(const bf16x8*)&sm[col * 66 + s * 16 + half * 8];
    *(bf16x8*)((char*)xb2 + ((size_t)n << 12) + t * 16) = o;
    if (t < NK) db[n * NK + t] = (__bf16)dist[n * NK + t];
  } else {
    const int kstep = blockIdx.x - NN;
    const int lane = t & 63;
    const int wv = t >> 6;
    const int o = wv * 32 + (lane & 31);
    const int kbase = kstep * 16 + (lane >> 5) * 8;
    bf16x8 r;
#pragma unroll
    for (int j = 0; j < 8; ++j) {
      const int kg = kbase + j;
      const int c = (kg < 2048) ? ((kg >> 6) * 65 + (kg & 63)) : ((kg - 2048) * 65 + 64);
      r[j] = (__bf16)W[(size_t)o * 2080 + c];
    }
    *(bf16x8*)(Wf + (((size_t)kstep * 256 + t) << 3)) = r;
  }
}

// ---------------------------------------------------------------------------
// Main: BARRIER-FREE streaming. Block = 128 threads = 2 waves = (2 n) x
// (kh = neighbor-half). Wave privately streams 16 neighbors: A gathered
// global->reg, B read global->reg (L1/L2-cached sequential stream), 8 MFMA
// per kstep (2 n x 4 og-groups), acc[2][4] f32x16 = 128 VGPR. NO mid-kernel
// sync: waves drift out of phase -> loads overlap MFMAs across waves;
// compiler pipelines freely. One final LDS reduction (kh=1 -> kh=0) + write.
// Grid 1000 -> ~7.8 waves/CU.
// ---------------------------------------------------------------------------
__global__ __launch_bounds__(128) void kmain(
    const int* __restrict__ nbrs, const float* __restrict__ bias,
    const __bf16* __restrict__ xb2, const __bf16* __restrict__ Wf,
    const __bf16* __restrict__ db, float* __restrict__ out) {
  __shared__ __align__(16) char red[32768];   // [np*4+og][lane*64 + q*16]

  const int t    = threadIdx.x;
  const int lane = t & 63;
  const int kh   = t >> 6;          // neighbor-half: c = kh*16 + cc
  const int col  = lane & 31;
  const int half = lane >> 5;
  const int n0   = blockIdx.x * 2;

  f32x16 acc00 = {}, acc01 = {}, acc02 = {}, acc03 = {};   // n0,   og0..3
  f32x16 acc10 = {}, acc11 = {}, acc12 = {}, acc13 = {};   // n0+1, og0..3

  // lanes 0-15: nbrs of n0 (c=kh*16+l); lanes 32-47: nbrs of n0+1
  int myidx = 0;
  if ((lane & 31) < 16)
    myidx = nbrs[(n0 + (lane >> 5)) * NK + kh * 16 + (lane & 15)];

  const char* xb = (const char*)xb2;
  const char* wf = (const char*)Wf + lane * 16;

  // ---- main stream: 16 neighbors x 4 ksteps, no synchronization
#pragma unroll 2
  for (int cc = 0; cc < 16; ++cc) {
    const int nbA = __builtin_amdgcn_readlane(myidx, cc);
    const int nbB = __builtin_amdgcn_readlane(myidx, 32 + cc);
    const char* gA = xb + ((size_t)nbA << 12) + lane * 16;
    const char* gB = xb + ((size_t)nbB << 12) + lane * 16;
    const char* wk = wf + ((size_t)((kh * 16 + cc) * 4) << 12);
#pragma unroll
    for (int ks = 0; ks < 4; ++ks) {
      bf16x8 a0 = *(const bf16x8*)(gA + (ks << 10));
      bf16x8 a1 = *(const bf16x8*)(gB + (ks << 10));
      bf16x8 b0 = *(const bf16x8*)(wk + (ks << 12));
      bf16x8 b1 = *(const bf16x8*)(wk + (ks << 12) + 1024);
      bf16x8 b2 = *(const bf16x8*)(wk + (ks << 12) + 2048);
      bf16x8 b3 = *(const bf16x8*)(wk + (ks << 12) + 3072);
      acc00 = MFMA32(a0, b0, acc00, 0, 0, 0);
      acc01 = MFMA32(a0, b1, acc01, 0, 0, 0);
      acc02 = MFMA32(a0, b2, acc02, 0, 0, 0);
      acc03 = MFMA32(a0, b3, acc03, 0, 0, 0);
      acc10 = MFMA32(a1, b0, acc10, 0, 0, 0);
      acc11 = MFMA32(a1, b1, acc11, 0, 0, 0);
      acc12 = MFMA32(a1, b2, acc12, 0, 0, 0);
      acc13 = MFMA32(a1, b3, acc13, 0, 0, 0);
    }
  }

  // ---- distance ksteps 128,129 (kh=0 wave only; A rows all equal d[n][slice])
  if (kh == 0) {
#pragma unroll
    for (int s = 0; s < 2; ++s) {
      const char* wk = wf + ((size_t)(128 + s) << 12);
      bf16x8 d0 = *(const bf16x8*)((const char*)db + (size_t)n0 * 64 + s * 32 + half * 16);
      bf16x8 d1 = *(const bf16x8*)((const char*)db + (size_t)(n0 + 1) * 64 + s * 32 + half * 16);
      bf16x8 b0 = *(const bf16x8*)(wk);
      bf16x8 b1 = *(const bf16x8*)(wk + 1024);
      bf16x8 b2 = *(const bf16x8*)(wk + 2048);
      bf16x8 b3 = *(const bf16x8*)(wk + 3072);
      acc00 = MFMA32(d0, b0, acc00, 0, 0, 0);
      acc01 = MFMA32(d0, b1, acc01, 0, 0, 0);
      acc02 = MFMA32(d0, b2, acc02, 0, 0, 0);
      acc03 = MFMA32(d0, b3, acc03, 0, 0, 0);
      acc10 = MFMA32(d1, b0, acc10, 0, 0, 0);
      acc11 = MFMA32(d1, b1, acc11, 0, 0, 0);
      acc12 = MFMA32(d1, b2, acc12, 0, 0, 0);
      acc13 = MFMA32(d1, b3, acc13, 0, 0, 0);
    }
  }

  // ---- kh reduction: kh=1 dumps acc to LDS; kh=0 adds + writes out.
  // Layout byte = slot*4096 + lane*64 + q*16 (lane stride 64B -> 2-way, free)
  if (kh == 1) {
    char* pb = red + lane * 64;
    f32x16* a[8] = {&acc00,&acc01,&acc02,&acc03,&acc10,&acc11,&acc12,&acc13};
#pragma unroll
    for (int sl = 0; sl < 8; ++sl) {
#pragma unroll
      for (int q = 0; q < 4; ++q) {
        f32x4 v;
        v[0] = (*a[sl])[q*4+0]; v[1] = (*a[sl])[q*4+1];
        v[2] = (*a[sl])[q*4+2]; v[3] = (*a[sl])[q*4+3];
        *(f32x4*)(pb + (sl << 12) + (q << 4)) = v;
      }
    }
  }
  __syncthreads();
  if (kh == 0) {
    const char* pb = red + lane * 64;
    f32x16* a[8] = {&acc00,&acc01,&acc02,&acc03,&acc10,&acc11,&acc12,&acc13};
#pragma unroll
    for (int sl = 0; sl < 8; ++sl) {
#pragma unroll
      for (int q = 0; q < 4; ++q) {
        f32x4 v = *(const f32x4*)(pb + (sl << 12) + (q << 4));
        (*a[sl])[q*4+0] += v[0]; (*a[sl])[q*4+1] += v[1];
        (*a[sl])[q*4+2] += v[2]; (*a[sl])[q*4+3] += v[3];
      }
    }
    // epilogue (R4/R6-verified): D col=lane&31 -> o=og*32+col,
    // row=(r&3)+8*(r>>2)+4*half -> batch
#pragma unroll
    for (int og = 0; og < 4; ++og) {
      const int o = og * 32 + col;
      const float bv = bias[o];
      const f32x16* c0 = (og==0)?&acc00:(og==1)?&acc01:(og==2)?&acc02:&acc03;
      const f32x16* c1 = (og==0)?&acc10:(og==1)?&acc11:(og==2)?&acc12:&acc13;
#pragma unroll
      for (int r = 0; r < 16; ++r) {
        const int row = (r & 3) + 8 * (r >> 2) + 4 * half;
        float* op = out + ((size_t)row * NN + n0) * NOUT + o;
        op[0]    = (*c0)[r] + bv;
        op[NOUT] = (*c1)[r] + bv;
      }
    }
  }
}

// ---------------------------------------------------------------------------
extern "C" void kernel_launch(void* const* d_in, const int* in_sizes, int n_in,
                              void* d_out, int out_size, void* d_ws, size_t ws_size,
                              hipStream_t stream) {
  const float* x    = (const float*)d_in[0];
  const int*   nbrs = (const int*)d_in[1];
  const float* dist = (const float*)d_in[2];
  const float* W    = (const float*)d_in[3];
  const float* bias = (const float*)d_in[4];
  float* out = (float*)d_out;

  char* ws = (char*)d_ws;
  __bf16* xb2 = (__bf16*)(ws);                          // 2000*4096  = 8,192,000 B
  __bf16* Wf  = (__bf16*)(ws + 8192000);                // 130*256*16 =   532,480 B
  __bf16* db  = (__bf16*)(ws + 8192000 + 532480);       // 2000*32*2  =   128,000 B

  kprep<<<NN + NSTEP, 256, 0, stream>>>(x, dist, W, xb2, db, Wf);
  kmain<<<NN / 2, 128, 0, stream>>>(nbrs, bias, xb2, Wf, db, out);
}

// Round 17
// 65.859 us; speedup vs baseline: 1.2050x; 1.2050x over previous
//
#include <hip/hip_runtime.h>
#include <hip/hip_bf16.h>
#include <stdint.h>

typedef __attribute__((ext_vector_type(8)))  __bf16   bf16x8;
typedef __attribute__((ext_vector_type(4)))  float    f32x4;
typedef __attribute__((ext_vector_type(8)))  float    f32x8;

#define NN   2000
#define NK   32
#define NOUT 128

#define GLOBAL_AS __attribute__((address_space(1)))
#define LDS_AS    __attribute__((address_space(3)))
#define SB() __builtin_amdgcn_sched_barrier(0)
#define MFMA16 __builtin_amdgcn_mfma_f32_16x16x32_bf16

// ---------------------------------------------------------------------------
// Prep (verified R12-R15). Blocks [0,NN): x -> xb2h[h][n] 2KB half-tiles in
// 16x16x32 A-frag order + dist -> db bf16. Blocks [NN,NN+65): W -> Wf2
// B-frag order: byte = kstep*8192 + og*1024 + lane*16 + j*2 holds
// W[o=og*16+(l&15)][col(kg=kstep*32+(l>>4)*8+j)].
// ---------------------------------------------------------------------------
__global__ void kprep(const float* __restrict__ x, const float* __restrict__ dist,
                      const float* __restrict__ W,
                      __bf16* __restrict__ xb2h, __bf16* __restrict__ db,
                      __bf16* __restrict__ Wf2) {
  const int t = threadIdx.x;
  if (blockIdx.x < NN) {
    const int n = blockIdx.x;
    const int b  = t >> 3;          // batch 0..31
    const int f0 = (t & 7) << 3;    // feature start 0..56
    const float* src = x + ((size_t)b * NN + n) * 64 + f0;
    f32x8 v = *(const f32x8*)src;
    bf16x8 r;
#pragma unroll
    for (int j = 0; j < 8; ++j) r[j] = (__bf16)v[j];
    const int h = b >> 4, row = b & 15;
    const int off = ((f0 >> 5) << 10) + (((((f0 >> 3) & 3) << 4) + row) << 4);
    *(bf16x8*)((char*)xb2h + ((size_t)(h * NN + n) << 11) + off) = r;
    if (t < NK) db[n * NK + t] = (__bf16)dist[n * NK + t];
  } else {
    const int kstep = blockIdx.x - NN;      // 0..64
#pragma unroll
    for (int pass = 0; pass < 2; ++pass) {
      const int it = t + pass * 256;
      const int og = it >> 6, lane = it & 63;
      const int o  = og * 16 + (lane & 15);
      const int kb = kstep * 32 + ((lane >> 4) << 3);
      bf16x8 r;
#pragma unroll
      for (int j = 0; j < 8; ++j) {
        const int kg = kb + j;
        const int col = (kg < 2048) ? ((kg >> 6) * 65 + (kg & 63)) : ((kg - 2048) * 65 + 64);
        r[j] = (__bf16)W[(size_t)o * 2080 + col];
      }
      *(bf16x8*)((char*)Wf2 + (size_t)kstep * 8192 + og * 1024 + lane * 16) = r;
    }
  }
}

// ---------------------------------------------------------------------------
// Main (R13 structure, verified; single change: A-gathers are NON-TEMPORAL
// -> no L1 allocation, relieves MSHR pressure from the random 1KB loads).
// Block = (half h, 8 n), 4 waves; wave = 2 n x ALL 128 out.
// A: nt global->reg, depth-3 in 4 named banks; B: global_load_lds depth-2
// in 3 LDS bufs. Steady queue at wait:
// [A(c):4,B(c):4,A(c+1):4,B(c+1):4,A(c+2):4]=20 -> vmcnt(12) drains A(c),B(c).
// ---------------------------------------------------------------------------
__global__ __launch_bounds__(256, 2) void kmain(
    const int* __restrict__ nbrs, const float* __restrict__ bias,
    const __bf16* __restrict__ xb2h, const __bf16* __restrict__ Wf2,
    const __bf16* __restrict__ db, float* __restrict__ out) {
  __shared__ __align__(16) char lds[3][16384];   // [buf][2 kstep][8 og][1KB]

  const int t    = threadIdx.x;
  const int lane = t & 63;
  const int w    = t >> 6;
  const int h    = blockIdx.x & 1;
  const int n0   = (blockIdx.x >> 1) * 8 + w * 2;
  const int colo = lane & 15;
  const int rgrp = lane >> 4;

  f32x4 acc[2][8] = {};                     // [np][og], literal-indexed only

  const int myidx = nbrs[(n0 + (lane >> 5)) * NK + (lane & 31)];

  const char* xb = (const char*)xb2h + ((size_t)(h * NN) << 11);
  const char* wf = (const char*)Wf2;

  auto loadA = [&](bf16x8 (*A)[2], int c) {   // 4 nt loads: 2 np x 2 ks (4KB)
#pragma unroll
    for (int np = 0; np < 2; ++np) {
      const int nb = __builtin_amdgcn_readlane(myidx, np * 32 + c);
      const char* g = xb + ((size_t)nb << 11) + lane * 16;
      A[np][0] = __builtin_nontemporal_load((const bf16x8*)(g));
      A[np][1] = __builtin_nontemporal_load((const bf16x8*)(g + 1024));
    }
  };

  auto stageB = [&](int buf, int c) {         // 16KB chunk (ksteps 2c,2c+1)
    const char* g = wf + ((size_t)c << 14) + (w << 12) + lane * 16;
    char* l = &lds[buf][w << 12];
#pragma unroll
    for (int q = 0; q < 4; ++q)
      __builtin_amdgcn_global_load_lds(
          (const GLOBAL_AS uint32_t*)(g + (q << 10)),
          (LDS_AS uint32_t*)(l + (q << 10)), 16, 0, 0);
  };

  auto compute = [&](int buf, bf16x8 (*A)[2]) {
    const char* lb = &lds[buf][lane * 16];
    __builtin_amdgcn_s_setprio(1);
#pragma unroll
    for (int ks = 0; ks < 2; ++ks) {
#pragma unroll
      for (int og = 0; og < 8; ++og) {
        bf16x8 bf = *(const bf16x8*)(lb + (ks << 13) + (og << 10));
        acc[0][og] = MFMA16(A[0][ks], bf, acc[0][og], 0, 0, 0);
        acc[1][og] = MFMA16(A[1][ks], bf, acc[1][og], 0, 0, 0);
      }
    }
    __builtin_amdgcn_s_setprio(0);
  };

  bf16x8 A0[2][2], A1[2][2], A2[2][2], A3[2][2];   // 4 named banks (64 VGPR)

  // prologue: queue = [A(0),B(0),A(1),B(1),A(2)] = 20 ops
  loadA(A0, 0); SB();
  stageB(0, 0); SB();
  loadA(A1, 1); SB();
  stageB(1, 1); SB();
  loadA(A2, 2); SB();

#define BODY(C, ACUR, ALD, BUFC, BUFS)                      \
  asm volatile("s_waitcnt vmcnt(12)" ::: "memory");         \
  __builtin_amdgcn_s_barrier(); SB();                       \
  stageB(BUFS, (C) + 2); SB();                              \
  loadA(ALD, (C) + 3); SB();                                \
  compute(BUFC, ACUR); SB();

  // steady periods 0..28 (bank = C&3, buf = C%3, stage buf = (C+2)%3)
  BODY( 0, A0, A3, 0, 2)  BODY( 1, A1, A0, 1, 0)  BODY( 2, A2, A1, 2, 1)
  BODY( 3, A3, A2, 0, 2)  BODY( 4, A0, A3, 1, 0)  BODY( 5, A1, A0, 2, 1)
  BODY( 6, A2, A1, 0, 2)  BODY( 7, A3, A2, 1, 0)  BODY( 8, A0, A3, 2, 1)
  BODY( 9, A1, A0, 0, 2)  BODY(10, A2, A1, 1, 0)  BODY(11, A3, A2, 2, 1)
  BODY(12, A0, A3, 0, 2)  BODY(13, A1, A0, 1, 0)  BODY(14, A2, A1, 2, 1)
  BODY(15, A3, A2, 0, 2)  BODY(16, A0, A3, 1, 0)  BODY(17, A1, A0, 2, 1)
  BODY(18, A2, A1, 0, 2)  BODY(19, A3, A2, 1, 0)  BODY(20, A0, A3, 2, 1)
  BODY(21, A1, A0, 0, 2)  BODY(22, A2, A1, 1, 0)  BODY(23, A3, A2, 2, 1)
  BODY(24, A0, A3, 0, 2)  BODY(25, A1, A0, 1, 0)  BODY(26, A2, A1, 2, 1)
  BODY(27, A3, A2, 0, 2)  BODY(28, A0, A3, 1, 0)
#undef BODY

  // period 29: entry queue [A29,B29,A30,B30,A31]=20 -> vmcnt(12); stage B(31)
  asm volatile("s_waitcnt vmcnt(12)" ::: "memory");
  __builtin_amdgcn_s_barrier(); SB();
  stageB(1, 31); SB();
  compute(2, A1); SB();
  // period 30: queue [A30,B30,A31,B31]=16 -> vmcnt(8)
  asm volatile("s_waitcnt vmcnt(8)" ::: "memory");
  __builtin_amdgcn_s_barrier(); SB();
  compute(0, A2); SB();
  // period 31
  asm volatile("s_waitcnt vmcnt(0)" ::: "memory");
  __builtin_amdgcn_s_barrier(); SB();
  compute(1, A3);

  // ---- distance kstep 64: A rows all equal d[n][k-slice]; B direct global
  {
    const char* wt = wf + ((size_t)64 << 13) + lane * 16;
    bf16x8 d0 = *(const bf16x8*)((const char*)db + (size_t)(n0 + 0) * 64 + (rgrp << 4));
    bf16x8 d1 = *(const bf16x8*)((const char*)db + (size_t)(n0 + 1) * 64 + (rgrp << 4));
#pragma unroll
    for (int og = 0; og < 8; ++og) {
      bf16x8 bf = *(const bf16x8*)(wt + (og << 10));
      acc[0][og] = MFMA16(d0, bf, acc[0][og], 0, 0, 0);
      acc[1][og] = MFMA16(d1, bf, acc[1][og], 0, 0, 0);
    }
  }

  // ---- epilogue: D col=lane&15 -> o=og*16+colo, row=(lane>>4)*4+r -> batch
#pragma unroll
  for (int og = 0; og < 8; ++og) {
    const int o = (og << 4) + colo;
    const float bv = bias[o];
#pragma unroll
    for (int r = 0; r < 4; ++r) {
      const int b = (h << 4) + (rgrp << 2) + r;
      float* op = out + ((size_t)b * NN + n0) * NOUT + o;
      op[0]    = acc[0][og][r] + bv;
      op[NOUT] = acc[1][og][r] + bv;
    }
  }
}

// ---------------------------------------------------------------------------
extern "C" void kernel_launch(void* const* d_in, const int* in_sizes, int n_in,
                              void* d_out, int out_size, void* d_ws, size_t ws_size,
                              hipStream_t stream) {
  const float* x    = (const float*)d_in[0];
  const int*   nbrs = (const int*)d_in[1];
  const float* dist = (const float*)d_in[2];
  const float* W    = (const float*)d_in[3];
  const float* bias = (const float*)d_in[4];
  float* out = (float*)d_out;

  char* ws = (char*)d_ws;
  __bf16* xb2h = (__bf16*)(ws);                          // 2*2000*2048 = 8,192,000 B
  __bf16* Wf2  = (__bf16*)(ws + 8192000);                // 65*8192     =   532,480 B
  __bf16* db   = (__bf16*)(ws + 8192000 + 532480);       // 2000*32*2   =   128,000 B

  kprep<<<NN + 65, 256, 0, stream>>>(x, dist, W, xb2h, db, Wf2);
  kmain<<<(NN / 8) * 2, 256, 0, stream>>>(nbrs, bias, xb2h, Wf2, db, out);
}

// Round 18
// 63.831 us; speedup vs baseline: 1.2433x; 1.0318x over previous
//
#include <hip/hip_runtime.h>
#include <hip/hip_bf16.h>
#include <stdint.h>

typedef __attribute__((ext_vector_type(8)))  __bf16   bf16x8;
typedef __attribute__((ext_vector_type(4)))  float    f32x4;
typedef __attribute__((ext_vector_type(8)))  float    f32x8;

#define NN   2000
#define NK   32
#define NOUT 128

#define GLOBAL_AS __attribute__((address_space(1)))
#define LDS_AS    __attribute__((address_space(3)))
#define MFMA16 __builtin_amdgcn_mfma_f32_16x16x32_bf16

// ---------------------------------------------------------------------------
// Prep (verified R12-R17). Blocks [0,NN): x -> xb2h[h][n] 2KB half-tiles in
// 16x16x32 A-frag order + dist -> db bf16. Blocks [NN,NN+65): W -> Wf2
// B-frag order: byte = kstep*8192 + og*1024 + lane*16 + j*2 holds
// W[o=og*16+(l&15)][col(kg=kstep*32+(l>>4)*8+j)], kstep 0..64 (K=32 each).
// ---------------------------------------------------------------------------
__global__ void kprep(const float* __restrict__ x, const float* __restrict__ dist,
                      const float* __restrict__ W,
                      __bf16* __restrict__ xb2h, __bf16* __restrict__ db,
                      __bf16* __restrict__ Wf2) {
  const int t = threadIdx.x;
  if (blockIdx.x < NN) {
    const int n = blockIdx.x;
    const int b  = t >> 3;          // batch 0..31
    const int f0 = (t & 7) << 3;    // feature start 0..56
    const float* src = x + ((size_t)b * NN + n) * 64 + f0;
    f32x8 v = *(const f32x8*)src;
    bf16x8 r;
#pragma unroll
    for (int j = 0; j < 8; ++j) r[j] = (__bf16)v[j];
    const int h = b >> 4, row = b & 15;
    const int off = ((f0 >> 5) << 10) + (((((f0 >> 3) & 3) << 4) + row) << 4);
    *(bf16x8*)((char*)xb2h + ((size_t)(h * NN + n) << 11) + off) = r;
    if (t < NK) db[n * NK + t] = (__bf16)dist[n * NK + t];
  } else {
    const int kstep = blockIdx.x - NN;      // 0..64
#pragma unroll
    for (int pass = 0; pass < 2; ++pass) {
      const int it = t + pass * 256;
      const int og = it >> 6, lane = it & 63;
      const int o  = og * 16 + (lane & 15);
      const int kb = kstep * 32 + ((lane >> 4) << 3);
      bf16x8 r;
#pragma unroll
      for (int j = 0; j < 8; ++j) {
        const int kg = kb + j;
        const int col = (kg < 2048) ? ((kg >> 6) * 65 + (kg & 63)) : ((kg - 2048) * 65 + 64);
        r[j] = (__bf16)W[(size_t)o * 2080 + col];
      }
      *(bf16x8*)((char*)Wf2 + (size_t)kstep * 8192 + og * 1024 + lane * 16) = r;
    }
  }
}

// ---------------------------------------------------------------------------
// Main: ZERO-BARRIER wave-private pipeline. Block = (h, 8 n) = 4 independent
// waves; wave = 2 n x ALL 128 out (acc[2][8] f32x4 = 64 VGPR).
// Per kstep c (64 regular + distance tail):
//   [vmcnt(10) | readB bf[8] from own LDS buf | stageB(buf, c+2) |
//    16 MFMA | loadA(bank, c+2)]
// B: wave-PRIVATE 2x8KB LDS double-buffer via global_load_lds (the 4 waves
// stage the same chunks ~simultaneously -> L1 coalesces; no cross-wave sync).
// A: global->reg, 2 banks, refilled after consumption (WAR-safe).
// vmcnt(10) is per-wave exact: queue [B(c):8,A(c):2,B(c+1):8,A(c+1):2]=20.
// Waves drift freely; 8 waves/CU provide the overlap the barriers killed.
// ---------------------------------------------------------------------------
__global__ __launch_bounds__(256, 2) void kmain(
    const int* __restrict__ nbrs, const float* __restrict__ bias,
    const __bf16* __restrict__ xb2h, const __bf16* __restrict__ Wf2,
    const __bf16* __restrict__ db, float* __restrict__ out) {
  __shared__ __align__(16) char lds[4][2][8192];   // [wave][buf][8 og x 1KB]

  const int t    = threadIdx.x;
  const int lane = t & 63;
  const int w    = t >> 6;
  const int h    = blockIdx.x & 1;
  const int n0   = (blockIdx.x >> 1) * 8 + w * 2;
  const int colo = lane & 15;
  const int rgrp = lane >> 4;

  f32x4 acc[2][8] = {};                     // [np][og], literal-indexed only

  // lane = np*32 + c2 holds neighbor c2 (0..31) of n0+np
  const int myidx = nbrs[(n0 + (lane >> 5)) * NK + (lane & 31)];

  const char* xb = (const char*)xb2h + ((size_t)(h * NN) << 11);
  const char* wf = (const char*)Wf2;

  auto stageB = [&](int buf, int c) {       // wave-private 8KB of kstep c
    const char* g = wf + ((size_t)c << 13) + lane * 16;
    char* l = &lds[w][buf][0];
#pragma unroll
    for (int q = 0; q < 8; ++q)
      __builtin_amdgcn_global_load_lds(
          (const GLOBAL_AS uint32_t*)(g + (q << 10)),
          (LDS_AS uint32_t*)(l + (q << 10)), 16, 0, 0);
  };

  auto loadA = [&](bf16x8* A, int c) {      // 2 loads: neighbor c>>1, half c&1
#pragma unroll
    for (int np = 0; np < 2; ++np) {
      const int nb = __builtin_amdgcn_readlane(myidx, np * 32 + (c >> 1));
      A[np] = *(const bf16x8*)(xb + ((size_t)nb << 11) + ((c & 1) << 10) + lane * 16);
    }
  };

  bf16x8 A0[2], A1[2];

  // prologue: queue = [B(0):8, A(0):2, B(1):8, A(1):2] = 20
  stageB(0, 0); loadA(A0, 0);
  stageB(1, 1); loadA(A1, 1);

#define BODY(C, BUF, AC, LOAD_NEXT)                          \
  {                                                          \
    asm volatile("s_waitcnt vmcnt(10)" ::: "memory");        \
    const char* lb = &lds[w][BUF][lane * 16];                \
    bf16x8 bf0 = *(const bf16x8*)(lb);                       \
    bf16x8 bf1 = *(const bf16x8*)(lb + 1024);                \
    bf16x8 bf2 = *(const bf16x8*)(lb + 2048);                \
    bf16x8 bf3 = *(const bf16x8*)(lb + 3072);                \
    bf16x8 bf4 = *(const bf16x8*)(lb + 4096);                \
    bf16x8 bf5 = *(const bf16x8*)(lb + 5120);                \
    bf16x8 bf6 = *(const bf16x8*)(lb + 6144);                \
    bf16x8 bf7 = *(const bf16x8*)(lb + 7168);                \
    stageB(BUF, (C) + 2);                                    \
    __builtin_amdgcn_s_setprio(1);                           \
    acc[0][0] = MFMA16(AC[0], bf0, acc[0][0], 0, 0, 0);      \
    acc[1][0] = MFMA16(AC[1], bf0, acc[1][0], 0, 0, 0);      \
    acc[0][1] = MFMA16(AC[0], bf1, acc[0][1], 0, 0, 0);      \
    acc[1][1] = MFMA16(AC[1], bf1, acc[1][1], 0, 0, 0);      \
    acc[0][2] = MFMA16(AC[0], bf2, acc[0][2], 0, 0, 0);      \
    acc[1][2] = MFMA16(AC[1], bf2, acc[1][2], 0, 0, 0);      \
    acc[0][3] = MFMA16(AC[0], bf3, acc[0][3], 0, 0, 0);      \
    acc[1][3] = MFMA16(AC[1], bf3, acc[1][3], 0, 0, 0);      \
    acc[0][4] = MFMA16(AC[0], bf4, acc[0][4], 0, 0, 0);      \
    acc[1][4] = MFMA16(AC[1], bf4, acc[1][4], 0, 0, 0);      \
    acc[0][5] = MFMA16(AC[0], bf5, acc[0][5], 0, 0, 0);      \
    acc[1][5] = MFMA16(AC[1], bf5, acc[1][5], 0, 0, 0);      \
    acc[0][6] = MFMA16(AC[0], bf6, acc[0][6], 0, 0, 0);      \
    acc[1][6] = MFMA16(AC[1], bf6, acc[1][6], 0, 0, 0);      \
    acc[0][7] = MFMA16(AC[0], bf7, acc[0][7], 0, 0, 0);      \
    acc[1][7] = MFMA16(AC[1], bf7, acc[1][7], 0, 0, 0);      \
    __builtin_amdgcn_s_setprio(0);                           \
    if (LOAD_NEXT) loadA(AC, (C) + 2);                       \
  }

  // periods 0..61: steady (stage c+2, reload consumed bank for c+2)
  for (int c = 0; c < 62; c += 2) {
    BODY(c + 0, 0, A0, 1)
    BODY(c + 1, 1, A1, 1)
  }
  // period 62: stages B(64) (distance kstep) into buf0; no A(64) exists
  BODY(62, 0, A0, 0)
  // period 63: queue [B63:8, A63:2, B64:8] = 18 -> drain B63,A63 -> vmcnt(8)
  {
    asm volatile("s_waitcnt vmcnt(8)" ::: "memory");
    const char* lb = &lds[w][1][lane * 16];
    bf16x8 bfv[8];
#pragma unroll
    for (int og = 0; og < 8; ++og) bfv[og] = *(const bf16x8*)(lb + (og << 10));
#pragma unroll
    for (int og = 0; og < 8; ++og) {
      acc[0][og] = MFMA16(A1[0], bfv[og], acc[0][og], 0, 0, 0);
      acc[1][og] = MFMA16(A1[1], bfv[og], acc[1][og], 0, 0, 0);
    }
  }
  // distance kstep 64 (B already staged in buf0): A rows all equal d[n][slice]
  {
    asm volatile("s_waitcnt vmcnt(0)" ::: "memory");
    const char* lb = &lds[w][0][lane * 16];
    bf16x8 d0 = *(const bf16x8*)((const char*)db + (size_t)(n0 + 0) * 64 + (rgrp << 4));
    bf16x8 d1 = *(const bf16x8*)((const char*)db + (size_t)(n0 + 1) * 64 + (rgrp << 4));
#pragma unroll
    for (int og = 0; og < 8; ++og) {
      bf16x8 bf = *(const bf16x8*)(lb + (og << 10));
      acc[0][og] = MFMA16(d0, bf, acc[0][og], 0, 0, 0);
      acc[1][og] = MFMA16(d1, bf, acc[1][og], 0, 0, 0);
    }
  }

  // ---- epilogue (R12-verified): D col=lane&15 -> o=og*16+colo,
  //      row=(lane>>4)*4+r -> batch (h half)
#pragma unroll
  for (int og = 0; og < 8; ++og) {
    const int o = (og << 4) + colo;
    const float bv = bias[o];
#pragma unroll
    for (int r = 0; r < 4; ++r) {
      const int b = (h << 4) + (rgrp << 2) + r;
      float* op = out + ((size_t)b * NN + n0) * NOUT + o;
      op[0]    = acc[0][og][r] + bv;
      op[NOUT] = acc[1][og][r] + bv;
    }
  }
}

// ---------------------------------------------------------------------------
extern "C" void kernel_launch(void* const* d_in, const int* in_sizes, int n_in,
                              void* d_out, int out_size, void* d_ws, size_t ws_size,
                              hipStream_t stream) {
  const float* x    = (const float*)d_in[0];
  const int*   nbrs = (const int*)d_in[1];
  const float* dist = (const float*)d_in[2];
  const float* W    = (const float*)d_in[3];
  const float* bias = (const float*)d_in[4];
  float* out = (float*)d_out;

  char* ws = (char*)d_ws;
  __bf16* xb2h = (__bf16*)(ws);                          // 2*2000*2048 = 8,192,000 B
  __bf16* Wf2  = (__bf16*)(ws + 8192000);                // 65*8192     =   532,480 B
  __bf16* db   = (__bf16*)(ws + 8192000 + 532480);       // 2000*32*2   =   128,000 B

  kprep<<<NN + 65, 256, 0, stream>>>(x, dist, W, xb2h, db, Wf2);
  kmain<<<(NN / 8) * 2, 256, 0, stream>>>(nbrs, bias, xb2h, Wf2, db, out);
}

// Round 19
// 52.312 us; speedup vs baseline: 1.5170x; 1.2202x over previous
//
#include <hip/hip_runtime.h>
#include <hip/hip_bf16.h>
#include <stdint.h>

typedef __attribute__((ext_vector_type(8)))  __bf16   bf16x8;
typedef __attribute__((ext_vector_type(4)))  float    f32x4;
typedef __attribute__((ext_vector_type(8)))  float    f32x8;

#define NN   2000
#define NK   32
#define NOUT 128

#define GLOBAL_AS __attribute__((address_space(1)))
#define LDS_AS    __attribute__((address_space(3)))
#define SB() __builtin_amdgcn_sched_barrier(0)
#define MFMA16 __builtin_amdgcn_mfma_f32_16x16x32_bf16

// ---------------------------------------------------------------------------
// Prep (verified R12-R18). Blocks [0,NN): x -> xb2h[h][n] 2KB half-tiles in
// 16x16x32 A-frag order + dist -> db bf16. Blocks [NN,NN+65): W -> Wf2
// B-frag order: byte = kstep*8192 + og*1024 + lane*16 + j*2 holds
// W[o=og*16+(l&15)][col(kg=kstep*32+(l>>4)*8+j)].
// ---------------------------------------------------------------------------
__global__ void kprep(const float* __restrict__ x, const float* __restrict__ dist,
                      const float* __restrict__ W,
                      __bf16* __restrict__ xb2h, __bf16* __restrict__ db,
                      __bf16* __restrict__ Wf2) {
  const int t = threadIdx.x;
  if (blockIdx.x < NN) {
    const int n = blockIdx.x;
    const int b  = t >> 3;          // batch 0..31
    const int f0 = (t & 7) << 3;    // feature start 0..56
    const float* src = x + ((size_t)b * NN + n) * 64 + f0;
    f32x8 v = *(const f32x8*)src;
    bf16x8 r;
#pragma unroll
    for (int j = 0; j < 8; ++j) r[j] = (__bf16)v[j];
    const int h = b >> 4, row = b & 15;
    const int off = ((f0 >> 5) << 10) + (((((f0 >> 3) & 3) << 4) + row) << 4);
    *(bf16x8*)((char*)xb2h + ((size_t)(h * NN + n) << 11) + off) = r;
    if (t < NK) db[n * NK + t] = (__bf16)dist[n * NK + t];
  } else {
    const int kstep = blockIdx.x - NN;      // 0..64
#pragma unroll
    for (int pass = 0; pass < 2; ++pass) {
      const int it = t + pass * 256;
      const int og = it >> 6, lane = it & 63;
      const int o  = og * 16 + (lane & 15);
      const int kb = kstep * 32 + ((lane >> 4) << 3);
      bf16x8 r;
#pragma unroll
      for (int j = 0; j < 8; ++j) {
        const int kg = kb + j;
        const int col = (kg < 2048) ? ((kg >> 6) * 65 + (kg & 63)) : ((kg - 2048) * 65 + 64);
        r[j] = (__bf16)W[(size_t)o * 2080 + col];
      }
      *(bf16x8*)((char*)Wf2 + (size_t)kstep * 8192 + og * 1024 + lane * 16) = r;
    }
  }
}

// ---------------------------------------------------------------------------
// Main (best-measured config, R13): block = (half h, 8 n), 4 waves; wave =
// 2 n x ALL 128 out. A (random gather) depth-3 in 4 named register banks;
// B (Wf2 stream) via global_load_lds, depth-2 in 3 LDS bufs.
// Steady queue at each wait: [A(c):4,B(c):4,A(c+1):4,B(c+1):4,A(c+2):4]=20
// -> vmcnt(12) drains exactly A(c),B(c); 12 ops stay in flight across the
// barrier. Fully unrolled 29 steady bodies + counted tails.
// ---------------------------------------------------------------------------
__global__ __launch_bounds__(256, 2) void kmain(
    const int* __restrict__ nbrs, const float* __restrict__ bias,
    const __bf16* __restrict__ xb2h, const __bf16* __restrict__ Wf2,
    const __bf16* __restrict__ db, float* __restrict__ out) {
  __shared__ __align__(16) char lds[3][16384];   // [buf][2 kstep][8 og][1KB]

  const int t    = threadIdx.x;
  const int lane = t & 63;
  const int w    = t >> 6;
  const int h    = blockIdx.x & 1;
  const int n0   = (blockIdx.x >> 1) * 8 + w * 2;
  const int colo = lane & 15;
  const int rgrp = lane >> 4;

  f32x4 acc[2][8] = {};                     // [np][og], literal-indexed only

  const int myidx = nbrs[(n0 + (lane >> 5)) * NK + (lane & 31)];

  const char* xb = (const char*)xb2h + ((size_t)(h * NN) << 11);
  const char* wf = (const char*)Wf2;

  auto loadA = [&](bf16x8 (*A)[2], int c) {   // 4 loads: 2 np x 2 ks (4KB)
#pragma unroll
    for (int np = 0; np < 2; ++np) {
      const int nb = __builtin_amdgcn_readlane(myidx, np * 32 + c);
      const char* g = xb + ((size_t)nb << 11) + lane * 16;
      A[np][0] = *(const bf16x8*)(g);
      A[np][1] = *(const bf16x8*)(g + 1024);
    }
  };

  auto stageB = [&](int buf, int c) {         // 16KB chunk (ksteps 2c,2c+1)
    const char* g = wf + ((size_t)c << 14) + (w << 12) + lane * 16;
    char* l = &lds[buf][w << 12];
#pragma unroll
    for (int q = 0; q < 4; ++q)
      __builtin_amdgcn_global_load_lds(
          (const GLOBAL_AS uint32_t*)(g + (q << 10)),
          (LDS_AS uint32_t*)(l + (q << 10)), 16, 0, 0);
  };

  auto compute = [&](int buf, bf16x8 (*A)[2]) {
    const char* lb = &lds[buf][lane * 16];
    __builtin_amdgcn_s_setprio(1);
#pragma unroll
    for (int ks = 0; ks < 2; ++ks) {
#pragma unroll
      for (int og = 0; og < 8; ++og) {
        bf16x8 bf = *(const bf16x8*)(lb + (ks << 13) + (og << 10));
        acc[0][og] = MFMA16(A[0][ks], bf, acc[0][og], 0, 0, 0);
        acc[1][og] = MFMA16(A[1][ks], bf, acc[1][og], 0, 0, 0);
      }
    }
    __builtin_amdgcn_s_setprio(0);
  };

  bf16x8 A0[2][2], A1[2][2], A2[2][2], A3[2][2];   // 4 named banks (64 VGPR)

  // prologue: queue = [A(0),B(0),A(1),B(1),A(2)] = 20 ops
  loadA(A0, 0); SB();
  stageB(0, 0); SB();
  loadA(A1, 1); SB();
  stageB(1, 1); SB();
  loadA(A2, 2); SB();

#define BODY(C, ACUR, ALD, BUFC, BUFS)                      \
  asm volatile("s_waitcnt vmcnt(12)" ::: "memory");         \
  __builtin_amdgcn_s_barrier(); SB();                       \
  stageB(BUFS, (C) + 2); SB();                              \
  loadA(ALD, (C) + 3); SB();                                \
  compute(BUFC, ACUR); SB();

  // steady periods 0..28 (bank = C&3, buf = C%3, stage buf = (C+2)%3)
  BODY( 0, A0, A3, 0, 2)  BODY( 1, A1, A0, 1, 0)  BODY( 2, A2, A1, 2, 1)
  BODY( 3, A3, A2, 0, 2)  BODY( 4, A0, A3, 1, 0)  BODY( 5, A1, A0, 2, 1)
  BODY( 6, A2, A1, 0, 2)  BODY( 7, A3, A2, 1, 0)  BODY( 8, A0, A3, 2, 1)
  BODY( 9, A1, A0, 0, 2)  BODY(10, A2, A1, 1, 0)  BODY(11, A3, A2, 2, 1)
  BODY(12, A0, A3, 0, 2)  BODY(13, A1, A0, 1, 0)  BODY(14, A2, A1, 2, 1)
  BODY(15, A3, A2, 0, 2)  BODY(16, A0, A3, 1, 0)  BODY(17, A1, A0, 2, 1)
  BODY(18, A2, A1, 0, 2)  BODY(19, A3, A2, 1, 0)  BODY(20, A0, A3, 2, 1)
  BODY(21, A1, A0, 0, 2)  BODY(22, A2, A1, 1, 0)  BODY(23, A3, A2, 2, 1)
  BODY(24, A0, A3, 0, 2)  BODY(25, A1, A0, 1, 0)  BODY(26, A2, A1, 2, 1)
  BODY(27, A3, A2, 0, 2)  BODY(28, A0, A3, 1, 0)
#undef BODY

  // period 29: entry queue [A29,B29,A30,B30,A31]=20 -> vmcnt(12); stage B(31)
  asm volatile("s_waitcnt vmcnt(12)" ::: "memory");
  __builtin_amdgcn_s_barrier(); SB();
  stageB(1, 31); SB();
  compute(2, A1); SB();
  // period 30: queue [A30,B30,A31,B31]=16 -> vmcnt(8)
  asm volatile("s_waitcnt vmcnt(8)" ::: "memory");
  __builtin_amdgcn_s_barrier(); SB();
  compute(0, A2); SB();
  // period 31
  asm volatile("s_waitcnt vmcnt(0)" ::: "memory");
  __builtin_amdgcn_s_barrier(); SB();
  compute(1, A3);

  // ---- distance kstep 64: A rows all equal d[n][k-slice]; B direct global
  {
    const char* wt = wf + ((size_t)64 << 13) + lane * 16;
    bf16x8 d0 = *(const bf16x8*)((const char*)db + (size_t)(n0 + 0) * 64 + (rgrp << 4));
    bf16x8 d1 = *(const bf16x8*)((const char*)db + (size_t)(n0 + 1) * 64 + (rgrp << 4));
#pragma unroll
    for (int og = 0; og < 8; ++og) {
      bf16x8 bf = *(const bf16x8*)(wt + (og << 10));
      acc[0][og] = MFMA16(d0, bf, acc[0][og], 0, 0, 0);
      acc[1][og] = MFMA16(d1, bf, acc[1][og], 0, 0, 0);
    }
  }

  // ---- epilogue: D col=lane&15 -> o=og*16+colo, row=(lane>>4)*4+r -> batch
#pragma unroll
  for (int og = 0; og < 8; ++og) {
    const int o = (og << 4) + colo;
    const float bv = bias[o];
#pragma unroll
    for (int r = 0; r < 4; ++r) {
      const int b = (h << 4) + (rgrp << 2) + r;
      float* op = out + ((size_t)b * NN + n0) * NOUT + o;
      op[0]    = acc[0][og][r] + bv;
      op[NOUT] = acc[1][og][r] + bv;
    }
  }
}

// ---------------------------------------------------------------------------
extern "C" void kernel_launch(void* const* d_in, const int* in_sizes, int n_in,
                              void* d_out, int out_size, void* d_ws, size_t ws_size,
                              hipStream_t stream) {
  const float* x    = (const float*)d_in[0];
  const int*   nbrs = (const int*)d_in[1];
  const float* dist = (const float*)d_in[2];
  const float* W    = (const float*)d_in[3];
  const float* bias = (const float*)d_in[4];
  float* out = (float*)d_out;

  char* ws = (char*)d_ws;
  __bf16* xb2h = (__bf16*)(ws);                          // 2*2000*2048 = 8,192,000 B
  __bf16* Wf2  = (__bf16*)(ws + 8192000);                // 65*8192     =   532,480 B
  __bf16* db   = (__bf16*)(ws + 8192000 + 532480);       // 2000*32*2   =   128,000 B

  kprep<<<NN + 65, 256, 0, stream>>>(x, dist, W, xb2h, db, Wf2);
  kmain<<<(NN / 8) * 2, 256, 0, stream>>>(nbrs, bias, xb2h, Wf2, db, out);
}